// Round 13
// baseline (200.804 us; speedup 1.0000x reference)
//
#include <hip/hip_runtime.h>
#include <math.h>

#define NROW 16384
#define DIM 2048
#define NLAB 20
#define T_INV 10.0f
#define PD_EPS 1e-6f
#define NORM_EPS 1e-12f

#define BLOCKS 1024
#define THREADS 256
#define WPB (THREADS / 64)            // 4 waves per block
#define TOTAL_WAVES (BLOCKS * WPB)    // 4096 -> 4 rows per wave, 2 iterations of 2 rows
#define FRAG 8                        // float4 per lane: DIM/4/64 = 8

// ws: float4 partials[BLOCKS]; every slot written every call (no atomics, no init).

__global__ __launch_bounds__(THREADS, 4) void clloss_main(const float* __restrict__ embed,
                                                          const int* __restrict__ labels,
                                                          float4* __restrict__ partials) {
    const int tid = threadIdx.x;
    const int lane = tid & 63;
    const int wid = tid >> 6;

    // ---- prologue: a-fragment (row0 normalized + eps) in registers ----
    // S_aa = inv^2*s + 2*eps*inv*sx + DIM*eps^2  (one combined reduce)
    const float4* row0 = (const float4*)embed;
    float4 a[FRAG];
#pragma unroll
    for (int it = 0; it < FRAG; ++it) a[it] = row0[it * 64 + lane];

    float s = 0.f, sx = 0.f;
#pragma unroll
    for (int it = 0; it < FRAG; ++it) {
        s  += a[it].x * a[it].x + a[it].y * a[it].y + a[it].z * a[it].z + a[it].w * a[it].w;
        sx += a[it].x + a[it].y + a[it].z + a[it].w;
    }
    for (int o = 32; o; o >>= 1) {
        s  += __shfl_xor(s,  o, 64);
        sx += __shfl_xor(sx, o, 64);
    }
    const float inv0 = 1.0f / fmaxf(sqrtf(s), NORM_EPS);
    const float S_aa = inv0 * inv0 * s + 2.0f * PD_EPS * inv0 * sx
                     + (float)DIM * PD_EPS * PD_EPS;
#pragma unroll
    for (int it = 0; it < FRAG; ++it) {
        a[it].x = a[it].x * inv0 + PD_EPS;
        a[it].y = a[it].y * inv0 + PD_EPS;
        a[it].z = a[it].z * inv0 + PD_EPS;
        a[it].w = a[it].w * inv0 + PD_EPS;
    }
    const float lab0 = (lane < NLAB) ? (float)labels[lane] : 0.f;

    // ---- main loop: 2 halves × 2 rows in flight (6 parallel reduce chains) ----
    const int gw = blockIdx.x * WPB + wid;
    float acc_e = 0.f, acc_c = 0.f, acc_cl = 0.f;

#pragma unroll
    for (int half = 0; half < 2; ++half) {
        const int rA = 1 + gw + half * 2 * TOTAL_WAVES;          // always < NROW
        const int rB = rA + TOTAL_WAVES;
        const bool vB = rB < NROW;                                // wave-uniform; false only for gw=4095,half=1
        const int rBc = vB ? rB : 0;

        const float4* pA = (const float4*)(embed + (size_t)rA * DIM);
        const float4* pB = (const float4*)(embed + (size_t)rBc * DIM);

        float4 bA[FRAG], bB[FRAG];
#pragma unroll
        for (int it = 0; it < FRAG; ++it) bA[it] = pA[it * 64 + lane];
#pragma unroll
        for (int it = 0; it < FRAG; ++it) bB[it] = pB[it * 64 + lane];

        float cA = (lane < NLAB) ? lab0 * (float)labels[rA * NLAB + lane] : 0.f;
        float cB = (lane < NLAB) ? lab0 * (float)labels[rBc * NLAB + lane] : 0.f;

        float sabA = 0.f, sbbA = 0.f, sabB = 0.f, sbbB = 0.f;
#pragma unroll
        for (int it = 0; it < FRAG; ++it) {
            sabA += a[it].x * bA[it].x + a[it].y * bA[it].y
                  + a[it].z * bA[it].z + a[it].w * bA[it].w;
            sbbA += bA[it].x * bA[it].x + bA[it].y * bA[it].y
                  + bA[it].z * bA[it].z + bA[it].w * bA[it].w;
            sabB += a[it].x * bB[it].x + a[it].y * bB[it].y
                  + a[it].z * bB[it].z + a[it].w * bB[it].w;
            sbbB += bB[it].x * bB[it].x + bB[it].y * bB[it].y
                  + bB[it].z * bB[it].z + bB[it].w * bB[it].w;
        }
        // six independent shfl chains, interleaved for ILP
        for (int o = 32; o; o >>= 1) {
            sabA += __shfl_xor(sabA, o, 64);
            sbbA += __shfl_xor(sbbA, o, 64);
            cA   += __shfl_xor(cA,   o, 64);
            sabB += __shfl_xor(sabB, o, 64);
            sbbB += __shfl_xor(sbbB, o, 64);
            cB   += __shfl_xor(cB,   o, 64);
        }
        const float invA = 1.0f / fmaxf(sqrtf(sbbA), NORM_EPS);
        const float d2A = fmaxf(S_aa + invA * (invA * sbbA - 2.0f * sabA), 0.f);
        const float lsA = -sqrtf(d2A) * T_INV;
        const float invB = 1.0f / fmaxf(sqrtf(sbbB), NORM_EPS);
        const float d2B = fmaxf(S_aa + invB * (invB * sbbB - 2.0f * sabB), 0.f);
        const float lsB = -sqrtf(d2B) * T_INV;

        acc_e  += expf(lsA);
        acc_c  += cA;
        acc_cl += cA * lsA;
        if (vB) {
            acc_e  += expf(lsB);
            acc_c  += cB;
            acc_cl += cB * lsB;
        }
    }

    // ---- epilogue: per-block partial to a distinct slot ----
    __shared__ float wsum[WPB][3];
    if (lane == 0) {
        wsum[wid][0] = acc_e;
        wsum[wid][1] = acc_c;
        wsum[wid][2] = acc_cl;
    }
    __syncthreads();
    if (tid == 0) {
        float4 p;
        p.x = wsum[0][0] + wsum[1][0] + wsum[2][0] + wsum[3][0];
        p.y = wsum[0][1] + wsum[1][1] + wsum[2][1] + wsum[3][1];
        p.z = wsum[0][2] + wsum[1][2] + wsum[2][2] + wsum[3][2];
        p.w = 0.f;
        partials[blockIdx.x] = p;
    }
}

// 1 block folds BLOCKS partials -> scalar.
__global__ __launch_bounds__(THREADS) void clloss_final(const float4* __restrict__ partials,
                                                        float* __restrict__ out) {
    __shared__ float red[THREADS / 64][3];
    const int tid = threadIdx.x;
    const int lane = tid & 63, wid = tid >> 6;

    float se = 0.f, sc = 0.f, scl = 0.f;
    for (int i = tid; i < BLOCKS; i += THREADS) {
        float4 p = partials[i];
        se += p.x; sc += p.y; scl += p.z;
    }
    for (int o = 32; o; o >>= 1) {
        se  += __shfl_xor(se,  o, 64);
        sc  += __shfl_xor(sc,  o, 64);
        scl += __shfl_xor(scl, o, 64);
    }
    if (lane == 0) { red[wid][0] = se; red[wid][1] = sc; red[wid][2] = scl; }
    __syncthreads();
    if (tid == 0) {
        se = sc = scl = 0.f;
        for (int w = 0; w < THREADS / 64; ++w) {
            se += red[w][0]; sc += red[w][1]; scl += red[w][2];
        }
        float Ci = 1e-12f + sc;
        float Ei = 1e-12f + se;
        float Li = (sc * logf(Ei) - scl) / Ci;
        out[0] = Li / (float)NROW;
    }
}

extern "C" void kernel_launch(void* const* d_in, const int* in_sizes, int n_in,
                              void* d_out, int out_size, void* d_ws, size_t ws_size,
                              hipStream_t stream) {
    const float* embed = (const float*)d_in[0];
    const int* labels = (const int*)d_in[1];
    float* out = (float*)d_out;
    float4* partials = (float4*)d_ws;

    clloss_main<<<BLOCKS, THREADS, 0, stream>>>(embed, labels, partials);
    clloss_final<<<1, THREADS, 0, stream>>>(partials, out);
}

// Round 14
// 193.701 us; speedup vs baseline: 1.0367x; 1.0367x over previous
//
#include <hip/hip_runtime.h>
#include <math.h>

#define NROW 16384
#define DIM 2048
#define NLAB 20
#define T_INV 10.0f
#define PD_EPS 1e-6f
#define NORM_EPS 1e-12f

#define BLOCKS 2048
#define THREADS 256
#define WPB (THREADS / 64)            // 4 waves per block
#define TOTAL_WAVES (BLOCKS * WPB)    // 8192 -> 2 rows per wave, both in flight
#define FRAG 8                        // float4 per lane: DIM/4/64 = 8

// ws: float4 partials[BLOCKS]; every slot written every call (no atomics, no init).

__global__ __launch_bounds__(THREADS) void clloss_main(const float* __restrict__ embed,
                                                       const int* __restrict__ labels,
                                                       float4* __restrict__ partials) {
    const int tid = threadIdx.x;
    const int lane = tid & 63;
    const int wid = tid >> 6;

    // ---- prologue: a-fragment (row0 normalized + eps) in registers ----
    const float4* row0 = (const float4*)embed;
    float4 a[FRAG];
#pragma unroll
    for (int it = 0; it < FRAG; ++it) a[it] = row0[it * 64 + lane];

    float s = 0.f, sx = 0.f;
#pragma unroll
    for (int it = 0; it < FRAG; ++it) {
        s  += a[it].x * a[it].x + a[it].y * a[it].y + a[it].z * a[it].z + a[it].w * a[it].w;
        sx += a[it].x + a[it].y + a[it].z + a[it].w;
    }
    for (int o = 32; o; o >>= 1) {
        s  += __shfl_xor(s,  o, 64);
        sx += __shfl_xor(sx, o, 64);
    }
    const float inv0 = 1.0f / fmaxf(sqrtf(s), NORM_EPS);
    const float S_aa = inv0 * inv0 * s + 2.0f * PD_EPS * inv0 * sx
                     + (float)DIM * PD_EPS * PD_EPS;
#pragma unroll
    for (int it = 0; it < FRAG; ++it) {
        a[it].x = a[it].x * inv0 + PD_EPS;
        a[it].y = a[it].y * inv0 + PD_EPS;
        a[it].z = a[it].z * inv0 + PD_EPS;
        a[it].w = a[it].w * inv0 + PD_EPS;
    }
    const float lab0 = (lane < NLAB) ? (float)labels[lane] : 0.f;

    // ---- main body: both rows' loads issued up front (max MLP), then
    //      both reduce pipelines interleaved ----
    const int gw = blockIdx.x * WPB + wid;     // 0..8191
    const int rA = 1 + gw;                     // 1..8192, always valid
    const int rB = rA + TOTAL_WAVES;           // 8193..16384; invalid only for gw=8191
    const bool vB = rB < NROW;                 // wave-uniform
    const int rBc = vB ? rB : 0;

    const float4* pA = (const float4*)(embed + (size_t)rA * DIM);
    const float4* pB = (const float4*)(embed + (size_t)rBc * DIM);

    // 16 independent global loads + 2 label loads, all before any use
    float4 bA[FRAG], bB[FRAG];
#pragma unroll
    for (int it = 0; it < FRAG; ++it) bA[it] = pA[it * 64 + lane];
#pragma unroll
    for (int it = 0; it < FRAG; ++it) bB[it] = pB[it * 64 + lane];
    float cA = (lane < NLAB) ? lab0 * (float)labels[rA * NLAB + lane] : 0.f;
    float cB = (lane < NLAB) ? lab0 * (float)labels[rBc * NLAB + lane] : 0.f;

    float sabA = 0.f, sbbA = 0.f, sabB = 0.f, sbbB = 0.f;
#pragma unroll
    for (int it = 0; it < FRAG; ++it) {
        sabA += a[it].x * bA[it].x + a[it].y * bA[it].y
              + a[it].z * bA[it].z + a[it].w * bA[it].w;
        sbbA += bA[it].x * bA[it].x + bA[it].y * bA[it].y
              + bA[it].z * bA[it].z + bA[it].w * bA[it].w;
        sabB += a[it].x * bB[it].x + a[it].y * bB[it].y
              + a[it].z * bB[it].z + a[it].w * bB[it].w;
        sbbB += bB[it].x * bB[it].x + bB[it].y * bB[it].y
              + bB[it].z * bB[it].z + bB[it].w * bB[it].w;
    }
    // six independent shfl chains interleaved
    for (int o = 32; o; o >>= 1) {
        sabA += __shfl_xor(sabA, o, 64);
        sbbA += __shfl_xor(sbbA, o, 64);
        cA   += __shfl_xor(cA,   o, 64);
        sabB += __shfl_xor(sabB, o, 64);
        sbbB += __shfl_xor(sbbB, o, 64);
        cB   += __shfl_xor(cB,   o, 64);
    }
    const float invA = 1.0f / fmaxf(sqrtf(sbbA), NORM_EPS);
    const float d2A = fmaxf(S_aa + invA * (invA * sbbA - 2.0f * sabA), 0.f);
    const float lsA = -sqrtf(d2A) * T_INV;
    const float invB = 1.0f / fmaxf(sqrtf(sbbB), NORM_EPS);
    const float d2B = fmaxf(S_aa + invB * (invB * sbbB - 2.0f * sabB), 0.f);
    const float lsB = -sqrtf(d2B) * T_INV;

    float acc_e  = expf(lsA);
    float acc_c  = cA;
    float acc_cl = cA * lsA;
    if (vB) {
        acc_e  += expf(lsB);
        acc_c  += cB;
        acc_cl += cB * lsB;
    }

    // ---- epilogue: per-block partial to a distinct slot ----
    __shared__ float wsum[WPB][3];
    if (lane == 0) {
        wsum[wid][0] = acc_e;
        wsum[wid][1] = acc_c;
        wsum[wid][2] = acc_cl;
    }
    __syncthreads();
    if (tid == 0) {
        float4 p;
        p.x = wsum[0][0] + wsum[1][0] + wsum[2][0] + wsum[3][0];
        p.y = wsum[0][1] + wsum[1][1] + wsum[2][1] + wsum[3][1];
        p.z = wsum[0][2] + wsum[1][2] + wsum[2][2] + wsum[3][2];
        p.w = 0.f;
        partials[blockIdx.x] = p;
    }
}

// 1 block folds BLOCKS partials -> scalar.
__global__ __launch_bounds__(THREADS) void clloss_final(const float4* __restrict__ partials,
                                                        float* __restrict__ out) {
    __shared__ float red[THREADS / 64][3];
    const int tid = threadIdx.x;
    const int lane = tid & 63, wid = tid >> 6;

    float se = 0.f, sc = 0.f, scl = 0.f;
    for (int i = tid; i < BLOCKS; i += THREADS) {
        float4 p = partials[i];
        se += p.x; sc += p.y; scl += p.z;
    }
    for (int o = 32; o; o >>= 1) {
        se  += __shfl_xor(se,  o, 64);
        sc  += __shfl_xor(sc,  o, 64);
        scl += __shfl_xor(scl, o, 64);
    }
    if (lane == 0) { red[wid][0] = se; red[wid][1] = sc; red[wid][2] = scl; }
    __syncthreads();
    if (tid == 0) {
        se = sc = scl = 0.f;
        for (int w = 0; w < THREADS / 64; ++w) {
            se += red[w][0]; sc += red[w][1]; scl += red[w][2];
        }
        float Ci = 1e-12f + sc;
        float Ei = 1e-12f + se;
        float Li = (sc * logf(Ei) - scl) / Ci;
        out[0] = Li / (float)NROW;
    }
}

extern "C" void kernel_launch(void* const* d_in, const int* in_sizes, int n_in,
                              void* d_out, int out_size, void* d_ws, size_t ws_size,
                              hipStream_t stream) {
    const float* embed = (const float*)d_in[0];
    const int* labels = (const int*)d_in[1];
    float* out = (float*)d_out;
    float4* partials = (float4*)d_ws;

    clloss_main<<<BLOCKS, THREADS, 0, stream>>>(embed, labels, partials);
    clloss_final<<<1, THREADS, 0, stream>>>(partials, out);
}